// Round 8
// baseline (232.023 us; speedup 1.0000x reference)
//
#include <hip/hip_runtime.h>
#include <hip/hip_bf16.h>

#define BB 4
#define TT 4096
#define HH 2048
#define NSLOT 64
#define KD 256
#define VD 256
#define BT (BB*TT)
#define NEGV (-1e9f)
#define EPSV 1e-5f

typedef __attribute__((ext_vector_type(8))) short short8;
typedef __attribute__((ext_vector_type(4))) float floatx4;

union B8 { short8 v; unsigned short u[8]; };

__device__ inline unsigned short f2bf(float x) {
  unsigned u = __float_as_uint(x);
  return (unsigned short)((u + 0x7FFFu + ((u >> 16) & 1u)) >> 16);
}
__device__ inline float bf2f(unsigned short h) {
  return __uint_as_float(((unsigned)h) << 16);
}
__device__ inline void cvt8(const float4 a, const float4 b, B8& h, B8& l) {
  const float f[8] = {a.x, a.y, a.z, a.w, b.x, b.y, b.z, b.w};
#pragma unroll
  for (int j = 0; j < 8; ++j) {
    unsigned short hh = f2bf(f[j]);
    h.u[j] = hh;
    l.u[j] = f2bf(f[j] - bf2f(hh));
  }
}

// ---------------- mask dtype detection + conversion (16 blocks) -------------
__global__ void mask_convert_kernel(const void* valid_raw, const void* hist_raw,
                                    int* valid_int, int* hist_int) {
  __shared__ int mode_s;
  const int tid = threadIdx.x;
  if (tid == 0) {
    const unsigned int* w = (const unsigned int*)valid_raw;
    int all01 = 1, anyfloat = 0;
    for (int i = 0; i < 64; ++i) {
      unsigned int x = w[i];
      if (x != 0u && x != 1u) all01 = 0;
      if (x == 0x3F800000u) anyfloat = 1;
    }
    mode_s = all01 ? 0 : (anyfloat ? 1 : 2);
  }
  __syncthreads();
  const int mode = mode_s;
  if (blockIdx.x == 0) {
    const int* vi = (const int*)valid_raw;
    const float* vf = (const float*)valid_raw;
    const unsigned char* vb = (const unsigned char*)valid_raw;
    for (int i = tid; i < BB * NSLOT; i += blockDim.x)
      valid_int[i] = (mode == 0) ? (vi[i] != 0)
                   : (mode == 1) ? (vf[i] != 0.0f)
                                 : (vb[i] != 0);
  }
  {
    const int* vi = (const int*)hist_raw;
    const float* vf = (const float*)hist_raw;
    const unsigned char* vb = (const unsigned char*)hist_raw;
    const int base = blockIdx.x * 1024;
    for (int i = tid; i < 1024; i += blockDim.x) {
      const int g = base + i;
      hist_int[g] = (mode == 0) ? (vi[g] != 0)
                  : (mode == 1) ? (vf[g] != 0.0f)
                                : (vb[g] != 0);
    }
  }
}

// ---------------- PK[b,n,h] = sum_k keys[b,n,k] * Wq[k,h]  (fp32) -----------
__global__ __launch_bounds__(256) void pk_kernel(const float* __restrict__ keys,
                                                 const float* __restrict__ Wq,
                                                 float* __restrict__ PK) {
  const int b = blockIdx.x >> 5;
  const int h0 = (blockIdx.x & 31) * 64;
  __shared__ float ks[64][260];
  const int tid = threadIdx.x;
  const float* kb = keys + (size_t)b * 64 * 256;
  for (int i = tid; i < 64 * 64; i += 256) {
    const int n = i >> 6, k4 = (i & 63) * 4;
    *(float4*)&ks[n][k4] = *(const float4*)&kb[n * 256 + k4];
  }
  __syncthreads();
  const int h = h0 + (tid & 63);
  const int ng = tid >> 6;
  float acc[16] = {};
  for (int k = 0; k < 256; ++k) {
    const float wq = Wq[(size_t)k * HH + h];
#pragma unroll
    for (int i = 0; i < 16; ++i) acc[i] += ks[i * 4 + ng][k] * wq;
  }
#pragma unroll
  for (int i = 0; i < 16; ++i)
    PK[((size_t)b * 64 + i * 4 + ng) * HH + h] = acc[i];
}

// -------- prep: PK hi/lo frags (blk<256), V^T frags (256..383),
//          WoB linear bf16 (384..1407) --------------------------------------
__global__ __launch_bounds__(64) void frag_prep_kernel(
    const float* __restrict__ PK, const float* __restrict__ vals,
    const float* __restrict__ Wo,
    unsigned short* __restrict__ PKh, unsigned short* __restrict__ PKl,
    unsigned short* __restrict__ VtF, unsigned short* __restrict__ WoB) {
  const int lane = threadIdx.x, fr = lane & 15, hi4 = lane >> 4;
  const int blk = blockIdx.x;
  if (blk < 256) {
    const int b = blk >> 6, kc = blk & 63;
#pragma unroll
    for (int nt = 0; nt < 4; ++nt) {
      const float* src = &PK[((size_t)b * 64 + nt * 16 + fr) * HH + kc * 32 + hi4 * 8];
      const float4 a = *(const float4*)src;
      const float4 c = *(const float4*)(src + 4);
      B8 h, l;
      cvt8(a, c, h, l);
      const size_t off = (((size_t)(b * 64 + kc) * 4 + nt) * 64 + lane) * 8;
      *(short8*)&PKh[off] = h.v;
      *(short8*)&PKl[off] = l.v;
    }
  } else if (blk < 384) {
    const int q = blk - 256;
    const int b = q >> 5, vt = (q >> 1) & 15, kc = q & 1;
    B8 t;
#pragma unroll
    for (int j = 0; j < 8; ++j) {
      const int n = kc * 32 + hi4 * 8 + j;
      t.u[j] = f2bf(vals[((size_t)b * 64 + n) * 256 + vt * 16 + fr]);
    }
    *(short8*)&VtF[(((size_t)b * 16 + vt) * 2 + kc) * 512 + lane * 8] = t.v;
  } else {
    const int q = blk - 384;               // 0..1023, 512 elems each
    const float* src = &Wo[(size_t)q * 512 + lane * 8];
    const float4 a = *(const float4*)src;
    const float4 b2 = *(const float4*)(src + 4);
    B8 t;
    t.u[0] = f2bf(a.x); t.u[1] = f2bf(a.y); t.u[2] = f2bf(a.z); t.u[3] = f2bf(a.w);
    t.u[4] = f2bf(b2.x); t.u[5] = f2bf(b2.y); t.u[6] = f2bf(b2.z); t.u[7] = f2bf(b2.w);
    *(short8*)&WoB[(size_t)q * 512 + lane * 8] = t.v;
  }
}

// -------- attn v8: 16 tok/block, BK=128 staged A hi/lo, grid 1024 -----------
__global__ __launch_bounds__(256, 4) void attn_kernel(
    const float* __restrict__ hs,
    const unsigned short* __restrict__ PKh,
    const unsigned short* __restrict__ PKl,
    const unsigned short* __restrict__ VtF,
    const int* __restrict__ valid,
    const int* __restrict__ hist,
    __hip_bfloat16* __restrict__ retrB) {
  const int t0 = blockIdx.x * 16;
  const int b = blockIdx.x >> 8;           // 256 blocks per batch
  const int tid = threadIdx.x;
  const int w = tid >> 6, lane = tid & 63;
  const int fr = lane & 15, hi4 = lane >> 4;

  __shared__ __align__(16) unsigned short Ah[16][136], Al[16][136];
  __shared__ float S[16][68];
  __shared__ __align__(16) unsigned short P[16][88];

  floatx4 acc = (floatx4){0.f, 0.f, 0.f, 0.f};

  const int sr = tid >> 4;        // token row 0..15
  const int sg = tid & 15;        // 8-float col group
  const float* gbase = &hs[(size_t)(t0 + sr) * HH + sg * 8];

  float4 va0 = *(const float4*)gbase;
  float4 va1 = *(const float4*)(gbase + 4);

  for (int s = 0; s < 16; ++s) {
    if (s) __syncthreads();
    B8 h_, l_;
    cvt8(va0, va1, h_, l_);
    *(short8*)&Ah[sr][sg * 8] = h_.v;
    *(short8*)&Al[sr][sg * 8] = l_.v;
    if (s < 15) {
      va0 = *(const float4*)(gbase + (s + 1) * 128);
      va1 = *(const float4*)(gbase + (s + 1) * 128 + 4);
    }
    short8 bh[4], bl[4];
#pragma unroll
    for (int kcL = 0; kcL < 4; ++kcL) {
      const size_t off = ((size_t)(b * 64 + s * 4 + kcL) * 4 + w) * 512 + lane * 8;
      bh[kcL] = *(const short8*)&PKh[off];
      bl[kcL] = *(const short8*)&PKl[off];
    }
    __syncthreads();
#pragma unroll
    for (int kcL = 0; kcL < 4; ++kcL) {
      const short8 ah = *(const short8*)&Ah[fr][kcL * 32 + hi4 * 8];
      const short8 al = *(const short8*)&Al[fr][kcL * 32 + hi4 * 8];
      acc = __builtin_amdgcn_mfma_f32_16x16x32_bf16(ah, bh[kcL], acc, 0, 0, 0);
      acc = __builtin_amdgcn_mfma_f32_16x16x32_bf16(al, bh[kcL], acc, 0, 0, 0);
      acc = __builtin_amdgcn_mfma_f32_16x16x32_bf16(ah, bl[kcL], acc, 0, 0, 0);
    }
  }

  __syncthreads();
#pragma unroll
  for (int rr = 0; rr < 4; ++rr)
    S[hi4 * 4 + rr][w * 16 + fr] = acc[rr];
  __syncthreads();

  // softmax: wave w -> tokens w*4..w*4+3; lane = slot
  const int vmy = valid[b * 64 + lane];
  const unsigned long long bal = __ballot(vmy != 0);
  const float any = (bal != 0ull) ? 1.0f : 0.0f;
#pragma unroll
  for (int i = 0; i < 4; ++i) {
    const int tt = w * 4 + i;
    float s = vmy ? S[tt][lane] : NEGV;
    float m = s;
#pragma unroll
    for (int o = 32; o; o >>= 1) m = fmaxf(m, __shfl_xor(m, o));
    const float e = __expf(s - m);
    float sum = e;
#pragma unroll
    for (int o = 32; o; o >>= 1) sum += __shfl_xor(sum, o);
    P[tt][lane] = f2bf(e / sum * any);
  }
  __syncthreads();

  // PV: wave w -> v-tiles w*4..w*4+3 (cols w*64..+63)
  short8 pa[2];
#pragma unroll
  for (int ks = 0; ks < 2; ++ks)
    pa[ks] = *(const short8*)&P[fr][ks * 32 + hi4 * 8];
  floatx4 acc2[4];
#pragma unroll
  for (int j = 0; j < 4; ++j) acc2[j] = (floatx4){0.f, 0.f, 0.f, 0.f};
  const size_t vbase = (size_t)(b * 16) * 2 * 512 + lane * 8;
#pragma unroll
  for (int j = 0; j < 4; ++j) {
    const int vt = w * 4 + j;
    const short8 v0 = *(const short8*)&VtF[vbase + (size_t)(vt * 2 + 0) * 512];
    const short8 v1 = *(const short8*)&VtF[vbase + (size_t)(vt * 2 + 1) * 512];
    acc2[j] = __builtin_amdgcn_mfma_f32_16x16x32_bf16(pa[0], v0, acc2[j], 0, 0, 0);
    acc2[j] = __builtin_amdgcn_mfma_f32_16x16x32_bf16(pa[1], v1, acc2[j], 0, 0, 0);
  }
#pragma unroll
  for (int rr = 0; rr < 4; ++rr) {
    const int tok = t0 + hi4 * 4 + rr;
    const float allowed = hist[tok] ? 0.0f : 1.0f;
#pragma unroll
    for (int j = 0; j < 4; ++j)
      retrB[(size_t)tok * 256 + (w * 4 + j) * 16 + fr] =
          __float2bfloat16(acc2[j][rr] * allowed);
  }
}

// -------- gemm2 classic: x = retrB(16384x256) . WoB^T(2048x256) + hs --------
// 128x128 tile, BK=64, 4 waves (2x2), double-buffered swizzled LDS.
// OUTMODE 0: write x as bf16 to xB.  OUTMODE 1: write x fp32 to xO.
template<int OUTMODE>
__global__ __launch_bounds__(256) void gemm2_kernel(
    const unsigned short* __restrict__ A,   // retrB bf16 [16384][256]
    const unsigned short* __restrict__ Bw,  // WoB bf16 [2048][256]
    const float* __restrict__ RES,
    unsigned short* __restrict__ xB,
    float* __restrict__ xO) {
  const int bm = blockIdx.x >> 4, bn = blockIdx.x & 15;
  const int m0 = bm * 128, n0 = bn * 128;
  const int tid = threadIdx.x;
  const int wid = tid >> 6, lane = tid & 63;
  const int fr = lane & 15, hi4 = lane >> 4;
  const int wr = wid >> 1, wc = wid & 1;

  __shared__ unsigned short As[2][128 * 64];
  __shared__ unsigned short Bs[2][128 * 64];

  floatx4 acc[4][4];
#pragma unroll
  for (int m = 0; m < 4; ++m)
#pragma unroll
    for (int n = 0; n < 4; ++n) acc[m][n] = (floatx4){0.f, 0.f, 0.f, 0.f};

  // staging: thread covers rows (wid*32 + i*8 + (lane>>3)), chunk c = lane&7
  const int srow = wid * 32 + (lane >> 3);
  const int sc = lane & 7;

  short8 rgA[4], rgB[4];
#define GLOAD(t) do { \
    const int k0 = (t) * 64; \
    _Pragma("unroll") \
    for (int i = 0; i < 4; ++i) { \
      const int row = srow + i * 8; \
      rgA[i] = *(const short8*)&A[(size_t)(m0 + row) * 256 + k0 + sc * 8]; \
      rgB[i] = *(const short8*)&Bw[(size_t)(n0 + row) * 256 + k0 + sc * 8]; \
    } \
  } while (0)
#define LWRITE(buf) do { \
    _Pragma("unroll") \
    for (int i = 0; i < 4; ++i) { \
      const int row = srow + i * 8; \
      const int swz = (sc ^ (row & 7)) * 8; \
      *(short8*)&As[buf][row * 64 + swz] = rgA[i]; \
      *(short8*)&Bs[buf][row * 64 + swz] = rgB[i]; \
    } \
  } while (0)

  GLOAD(0);
  LWRITE(0);

#pragma unroll
  for (int t = 0; t < 4; ++t) {
    const int buf = t & 1;
    if (t < 3) GLOAD(t + 1);
    __syncthreads();
#pragma unroll
    for (int kk = 0; kk < 2; ++kk) {
      short8 af[4], bf[4];
#pragma unroll
      for (int m = 0; m < 4; ++m) {
        const int row = wr * 64 + m * 16 + fr;
        const int chunk = ((kk * 4 + hi4) ^ (row & 7)) * 8;
        af[m] = *(const short8*)&As[buf][row * 64 + chunk];
      }
#pragma unroll
      for (int n = 0; n < 4; ++n) {
        const int row = wc * 64 + n * 16 + fr;
        const int chunk = ((kk * 4 + hi4) ^ (row & 7)) * 8;
        bf[n] = *(const short8*)&Bs[buf][row * 64 + chunk];
      }
#pragma unroll
      for (int m = 0; m < 4; ++m)
#pragma unroll
        for (int n = 0; n < 4; ++n)
          acc[m][n] = __builtin_amdgcn_mfma_f32_16x16x32_bf16(af[m], bf[n],
                                                              acc[m][n], 0, 0, 0);
    }
    if (t < 3) {
      __syncthreads();
      LWRITE(buf ^ 1);
    }
  }

  // epilogue: x = acc + RES
#pragma unroll
  for (int m = 0; m < 4; ++m)
#pragma unroll
    for (int n = 0; n < 4; ++n)
#pragma unroll
      for (int rr = 0; rr < 4; ++rr) {
        const int row = m0 + wr * 64 + m * 16 + hi4 * 4 + rr;
        const int col = n0 + wc * 64 + n * 16 + fr;
        const size_t off = (size_t)row * HH + col;
        const float x = acc[m][n][rr] + RES[off];
        if constexpr (OUTMODE == 0) xB[off] = f2bf(x);
        else xO[off] = x;
      }
#undef GLOAD
#undef LWRITE
}

// -------- LN pass: stats + normalize. 8 rows/block, 256 thr -----------------
__global__ __launch_bounds__(256) void ln2_bf16_kernel(
    const unsigned short* __restrict__ xB,
    const float* __restrict__ gamma, const float* __restrict__ beta,
    float* __restrict__ out) {
  const int tid = threadIdx.x;
  const int row = blockIdx.x * 8 + (tid >> 5);
  const int c0 = (tid & 31) * 64;
  const unsigned short* xr = &xB[(size_t)row * HH + c0];
  float v[64];
  float s = 0.f, q = 0.f;
#pragma unroll
  for (int i = 0; i < 8; ++i) {
    B8 t;
    t.v = *(const short8*)&xr[i * 8];
#pragma unroll
    for (int j = 0; j < 8; ++j) {
      const float f = bf2f(t.u[j]);
      v[i * 8 + j] = f;
      s += f;
      q += f * f;
    }
  }
#pragma unroll
  for (int o = 1; o < 32; o <<= 1) {
    s += __shfl_xor(s, o);
    q += __shfl_xor(q, o);
  }
  const float mu = s * (1.0f / HH);
  const float inv = rsqrtf(q * (1.0f / HH) - mu * mu + EPSV);
  float* orow = &out[(size_t)row * HH + c0];
#pragma unroll
  for (int i = 0; i < 16; ++i) {
    const float4 g = *(const float4*)&gamma[c0 + i * 4];
    const float4 bb = *(const float4*)&beta[c0 + i * 4];
    float4 o4;
    o4.x = (v[i * 4 + 0] - mu) * inv * g.x + bb.x;
    o4.y = (v[i * 4 + 1] - mu) * inv * g.y + bb.y;
    o4.z = (v[i * 4 + 2] - mu) * inv * g.z + bb.z;
    o4.w = (v[i * 4 + 3] - mu) * inv * g.w + bb.w;
    *(float4*)&orow[i * 4] = o4;
  }
}

__global__ __launch_bounds__(256) void ln2_ip_kernel(
    float* __restrict__ x,
    const float* __restrict__ gamma, const float* __restrict__ beta) {
  const int tid = threadIdx.x;
  const int row = blockIdx.x * 8 + (tid >> 5);
  const int c0 = (tid & 31) * 64;
  float* xr = &x[(size_t)row * HH + c0];
  float v[64];
  float s = 0.f, q = 0.f;
#pragma unroll
  for (int i = 0; i < 16; ++i) {
    const float4 t = *(const float4*)&xr[i * 4];
    v[i * 4 + 0] = t.x; v[i * 4 + 1] = t.y;
    v[i * 4 + 2] = t.z; v[i * 4 + 3] = t.w;
    s += t.x + t.y + t.z + t.w;
    q += t.x * t.x + t.y * t.y + t.z * t.z + t.w * t.w;
  }
#pragma unroll
  for (int o = 1; o < 32; o <<= 1) {
    s += __shfl_xor(s, o);
    q += __shfl_xor(q, o);
  }
  const float mu = s * (1.0f / HH);
  const float inv = rsqrtf(q * (1.0f / HH) - mu * mu + EPSV);
#pragma unroll
  for (int i = 0; i < 16; ++i) {
    const float4 g = *(const float4*)&gamma[c0 + i * 4];
    const float4 bb = *(const float4*)&beta[c0 + i * 4];
    float4 o4;
    o4.x = (v[i * 4 + 0] - mu) * inv * g.x + bb.x;
    o4.y = (v[i * 4 + 1] - mu) * inv * g.y + bb.y;
    o4.z = (v[i * 4 + 2] - mu) * inv * g.z + bb.z;
    o4.w = (v[i * 4 + 3] - mu) * inv * g.w + bb.w;
    *(float4*)&xr[i * 4] = o4;
  }
}

extern "C" void kernel_launch(void* const* d_in, const int* in_sizes, int n_in,
                              void* d_out, int out_size, void* d_ws, size_t ws_size,
                              hipStream_t stream) {
  const float* hs    = (const float*)d_in[0];
  const float* keys  = (const float*)d_in[1];
  const float* vals  = (const float*)d_in[2];
  const float* Wq    = (const float*)d_in[3];
  const float* Wo    = (const float*)d_in[4];
  const float* gamma = (const float*)d_in[5];
  const float* beta  = (const float*)d_in[6];
  const void* valid_raw = d_in[7];
  const void* hist_raw  = d_in[8];
  float* out = (float*)d_out;

  char* w = (char*)d_ws;
  float* PK            = (float*)w;                           // 2 MB
  unsigned short* PKh  = (unsigned short*)(w + (2u << 20));   // 1 MB
  unsigned short* PKl  = (unsigned short*)(w + (3u << 20));   // 1 MB
  unsigned short* VtF  = (unsigned short*)(w + (4u << 20));   // 256 KB
  unsigned short* WoB  = (unsigned short*)(w + (4u << 20) + (512u << 10)); // 1 MB
  __hip_bfloat16* retrB = (__hip_bfloat16*)(w + (6u << 20));  // 8 MB
  int* valid_int = (int*)(w + (14u << 20));
  int* hist_int  = valid_int + BB * NSLOT;
  unsigned short* xB = (unsigned short*)(w + (15u << 20));    // 64 MB (optional)
  const bool bigws = ws_size >= ((size_t)80u << 20);

  mask_convert_kernel<<<dim3(16), dim3(256), 0, stream>>>(valid_raw, hist_raw,
                                                          valid_int, hist_int);
  pk_kernel<<<dim3(128), dim3(256), 0, stream>>>(keys, Wq, PK);
  frag_prep_kernel<<<dim3(1408), dim3(64), 0, stream>>>(PK, vals, Wo,
                                                        PKh, PKl, VtF, WoB);
  attn_kernel<<<dim3(BT / 16), dim3(256), 0, stream>>>(
      hs, PKh, PKl, VtF, valid_int, hist_int, retrB);
  if (bigws) {
    gemm2_kernel<0><<<dim3((BT / 128) * (HH / 128)), dim3(256), 0, stream>>>(
        (const unsigned short*)retrB, WoB, hs, xB, nullptr);
    ln2_bf16_kernel<<<dim3(BT / 8), dim3(256), 0, stream>>>(xB, gamma, beta, out);
  } else {
    gemm2_kernel<1><<<dim3((BT / 128) * (HH / 128)), dim3(256), 0, stream>>>(
        (const unsigned short*)retrB, WoB, hs, nullptr, out);
    ln2_ip_kernel<<<dim3(BT / 8), dim3(256), 0, stream>>>(out, gamma, beta);
  }
}

// Round 9
// 183.793 us; speedup vs baseline: 1.2624x; 1.2624x over previous
//
#include <hip/hip_runtime.h>
#include <hip/hip_bf16.h>

#define BB 4
#define TT 4096
#define HH 2048
#define NSLOT 64
#define KD 256
#define VD 256
#define BT (BB*TT)
#define NEGV (-1e9f)
#define EPSV 1e-5f

typedef __attribute__((ext_vector_type(8))) short short8;
typedef __attribute__((ext_vector_type(4))) float floatx4;

union B8 { short8 v; unsigned short u[8]; };

__device__ inline unsigned short f2bf(float x) {
  unsigned u = __float_as_uint(x);
  return (unsigned short)((u + 0x7FFFu + ((u >> 16) & 1u)) >> 16);
}
__device__ inline float bf2f(unsigned short h) {
  return __uint_as_float(((unsigned)h) << 16);
}
__device__ inline void cvt8(const float4 a, const float4 b, B8& h, B8& l) {
  const float f[8] = {a.x, a.y, a.z, a.w, b.x, b.y, b.z, b.w};
#pragma unroll
  for (int j = 0; j < 8; ++j) {
    unsigned short hh = f2bf(f[j]);
    h.u[j] = hh;
    l.u[j] = f2bf(f[j] - bf2f(hh));
  }
}

// ---------------- mask dtype detection + conversion (16 blocks) -------------
__global__ void mask_convert_kernel(const void* valid_raw, const void* hist_raw,
                                    int* valid_int, int* hist_int) {
  __shared__ int mode_s;
  const int tid = threadIdx.x;
  if (tid == 0) {
    const unsigned int* w = (const unsigned int*)valid_raw;
    int all01 = 1, anyfloat = 0;
    for (int i = 0; i < 64; ++i) {
      unsigned int x = w[i];
      if (x != 0u && x != 1u) all01 = 0;
      if (x == 0x3F800000u) anyfloat = 1;
    }
    mode_s = all01 ? 0 : (anyfloat ? 1 : 2);
  }
  __syncthreads();
  const int mode = mode_s;
  if (blockIdx.x == 0) {
    const int* vi = (const int*)valid_raw;
    const float* vf = (const float*)valid_raw;
    const unsigned char* vb = (const unsigned char*)valid_raw;
    for (int i = tid; i < BB * NSLOT; i += blockDim.x)
      valid_int[i] = (mode == 0) ? (vi[i] != 0)
                   : (mode == 1) ? (vf[i] != 0.0f)
                                 : (vb[i] != 0);
  }
  {
    const int* vi = (const int*)hist_raw;
    const float* vf = (const float*)hist_raw;
    const unsigned char* vb = (const unsigned char*)hist_raw;
    const int base = blockIdx.x * 1024;
    for (int i = tid; i < 1024; i += blockDim.x) {
      const int g = base + i;
      hist_int[g] = (mode == 0) ? (vi[g] != 0)
                  : (mode == 1) ? (vf[g] != 0.0f)
                                : (vb[g] != 0);
    }
  }
}

// ---------------- PK[b,n,h] = sum_k keys[b,n,k] * Wq[k,h]  (fp32) -----------
__global__ __launch_bounds__(256) void pk_kernel(const float* __restrict__ keys,
                                                 const float* __restrict__ Wq,
                                                 float* __restrict__ PK) {
  const int b = blockIdx.x >> 5;
  const int h0 = (blockIdx.x & 31) * 64;
  __shared__ float ks[64][260];
  const int tid = threadIdx.x;
  const float* kb = keys + (size_t)b * 64 * 256;
  for (int i = tid; i < 64 * 64; i += 256) {
    const int n = i >> 6, k4 = (i & 63) * 4;
    *(float4*)&ks[n][k4] = *(const float4*)&kb[n * 256 + k4];
  }
  __syncthreads();
  const int h = h0 + (tid & 63);
  const int ng = tid >> 6;
  float acc[16] = {};
  for (int k = 0; k < 256; ++k) {
    const float wq = Wq[(size_t)k * HH + h];
#pragma unroll
    for (int i = 0; i < 16; ++i) acc[i] += ks[i * 4 + ng][k] * wq;
  }
#pragma unroll
  for (int i = 0; i < 16; ++i)
    PK[((size_t)b * 64 + i * 4 + ng) * HH + h] = acc[i];
}

// -------- prep: PK hi/lo frags (blk<256), V^T frags (256..383),
//          WoB linear bf16 (384..1407) --------------------------------------
__global__ __launch_bounds__(64) void frag_prep_kernel(
    const float* __restrict__ PK, const float* __restrict__ vals,
    const float* __restrict__ Wo,
    unsigned short* __restrict__ PKh, unsigned short* __restrict__ PKl,
    unsigned short* __restrict__ VtF, unsigned short* __restrict__ WoB) {
  const int lane = threadIdx.x, fr = lane & 15, hi4 = lane >> 4;
  const int blk = blockIdx.x;
  if (blk < 256) {
    const int b = blk >> 6, kc = blk & 63;
#pragma unroll
    for (int nt = 0; nt < 4; ++nt) {
      const float* src = &PK[((size_t)b * 64 + nt * 16 + fr) * HH + kc * 32 + hi4 * 8];
      const float4 a = *(const float4*)src;
      const float4 c = *(const float4*)(src + 4);
      B8 h, l;
      cvt8(a, c, h, l);
      const size_t off = (((size_t)(b * 64 + kc) * 4 + nt) * 64 + lane) * 8;
      *(short8*)&PKh[off] = h.v;
      *(short8*)&PKl[off] = l.v;
    }
  } else if (blk < 384) {
    const int q = blk - 256;
    const int b = q >> 5, vt = (q >> 1) & 15, kc = q & 1;
    B8 t;
#pragma unroll
    for (int j = 0; j < 8; ++j) {
      const int n = kc * 32 + hi4 * 8 + j;
      t.u[j] = f2bf(vals[((size_t)b * 64 + n) * 256 + vt * 16 + fr]);
    }
    *(short8*)&VtF[(((size_t)b * 16 + vt) * 2 + kc) * 512 + lane * 8] = t.v;
  } else {
    const int q = blk - 384;               // 0..1023, 512 elems each
    const float* src = &Wo[(size_t)q * 512 + lane * 8];
    const float4 a = *(const float4*)src;
    const float4 b2 = *(const float4*)(src + 4);
    B8 t;
    t.u[0] = f2bf(a.x); t.u[1] = f2bf(a.y); t.u[2] = f2bf(a.z); t.u[3] = f2bf(a.w);
    t.u[4] = f2bf(b2.x); t.u[5] = f2bf(b2.y); t.u[6] = f2bf(b2.z); t.u[7] = f2bf(b2.w);
    *(short8*)&WoB[(size_t)q * 512 + lane * 8] = t.v;
  }
}

// -------- attn v9: 16 tok/block, double-buffered LDS A, PK reg prefetch -----
// one barrier per K-step; 3 independent MFMA accumulator chains; grid 1024
__global__ __launch_bounds__(256, 4) void attn_kernel(
    const float* __restrict__ hs,
    const unsigned short* __restrict__ PKh,
    const unsigned short* __restrict__ PKl,
    const unsigned short* __restrict__ VtF,
    const int* __restrict__ valid,
    const int* __restrict__ hist,
    __hip_bfloat16* __restrict__ retrB) {
  const int t0 = blockIdx.x * 16;
  const int b = blockIdx.x >> 8;           // 256 blocks per batch
  const int tid = threadIdx.x;
  const int w = tid >> 6, lane = tid & 63;
  const int fr = lane & 15, hi4 = lane >> 4;

  __shared__ __align__(16) unsigned short Ah[2][16][136], Al[2][16][136];
  __shared__ float S[16][68];
  __shared__ __align__(16) unsigned short P[16][88];

  floatx4 accA = (floatx4){0.f, 0.f, 0.f, 0.f};
  floatx4 accB = accA, accC = accA;

  const int sr = tid >> 4;        // token row 0..15
  const int sg = tid & 15;        // 8-float col group
  const float* gbase = &hs[(size_t)(t0 + sr) * HH + sg * 8];

  // prologue: A[0] -> LDS[0]; va <- A[1]; pk cur <- PK[0]
  float4 va0 = *(const float4*)gbase;
  float4 va1 = *(const float4*)(gbase + 4);
  {
    B8 h_, l_;
    cvt8(va0, va1, h_, l_);
    *(short8*)&Ah[0][sr][sg * 8] = h_.v;
    *(short8*)&Al[0][sr][sg * 8] = l_.v;
  }
  va0 = *(const float4*)(gbase + 128);
  va1 = *(const float4*)(gbase + 132);
  short8 bhc[4], blc[4];
#pragma unroll
  for (int kcL = 0; kcL < 4; ++kcL) {
    const size_t off = ((size_t)(b * 64 + kcL) * 4 + w) * 512 + lane * 8;
    bhc[kcL] = *(const short8*)&PKh[off];
    blc[kcL] = *(const short8*)&PKl[off];
  }
  __syncthreads();

  for (int s = 0; s < 16; ++s) {
    const int buf = s & 1;
    // write A[s+1] into LDS[buf^1] (no hazard: other buffer)
    if (s < 15) {
      B8 h_, l_;
      cvt8(va0, va1, h_, l_);
      *(short8*)&Ah[buf ^ 1][sr][sg * 8] = h_.v;
      *(short8*)&Al[buf ^ 1][sr][sg * 8] = l_.v;
    }
    // issue A[s+2] global loads (hidden under MFMAs)
    if (s < 14) {
      va0 = *(const float4*)(gbase + (s + 2) * 128);
      va1 = *(const float4*)(gbase + (s + 2) * 128 + 4);
    }
    // issue PK[s+1] prefetch (L2 latency hidden under MFMAs)
    short8 bhn[4], bln[4];
    if (s < 15) {
#pragma unroll
      for (int kcL = 0; kcL < 4; ++kcL) {
        const size_t off = ((size_t)(b * 64 + (s + 1) * 4 + kcL) * 4 + w) * 512 + lane * 8;
        bhn[kcL] = *(const short8*)&PKh[off];
        bln[kcL] = *(const short8*)&PKl[off];
      }
    }
    // MFMAs on LDS[buf] x pk cur — 3 independent chains
#pragma unroll
    for (int kcL = 0; kcL < 4; ++kcL) {
      const short8 ah = *(const short8*)&Ah[buf][fr][kcL * 32 + hi4 * 8];
      const short8 al = *(const short8*)&Al[buf][fr][kcL * 32 + hi4 * 8];
      accA = __builtin_amdgcn_mfma_f32_16x16x32_bf16(ah, bhc[kcL], accA, 0, 0, 0);
      accB = __builtin_amdgcn_mfma_f32_16x16x32_bf16(al, bhc[kcL], accB, 0, 0, 0);
      accC = __builtin_amdgcn_mfma_f32_16x16x32_bf16(ah, blc[kcL], accC, 0, 0, 0);
    }
    __syncthreads();
    if (s < 15) {
#pragma unroll
      for (int kcL = 0; kcL < 4; ++kcL) { bhc[kcL] = bhn[kcL]; blc[kcL] = bln[kcL]; }
    }
  }

  const floatx4 acc = accA + accB + accC;
#pragma unroll
  for (int rr = 0; rr < 4; ++rr)
    S[hi4 * 4 + rr][w * 16 + fr] = acc[rr];
  __syncthreads();

  // softmax: wave w -> tokens w*4..w*4+3; lane = slot
  const int vmy = valid[b * 64 + lane];
  const unsigned long long bal = __ballot(vmy != 0);
  const float any = (bal != 0ull) ? 1.0f : 0.0f;
#pragma unroll
  for (int i = 0; i < 4; ++i) {
    const int tt = w * 4 + i;
    float s = vmy ? S[tt][lane] : NEGV;
    float m = s;
#pragma unroll
    for (int o = 32; o; o >>= 1) m = fmaxf(m, __shfl_xor(m, o));
    const float e = __expf(s - m);
    float sum = e;
#pragma unroll
    for (int o = 32; o; o >>= 1) sum += __shfl_xor(sum, o);
    P[tt][lane] = f2bf(e / sum * any);
  }
  __syncthreads();

  // PV: wave w -> v-tiles w*4..w*4+3 (cols w*64..+63)
  short8 pa[2];
#pragma unroll
  for (int ks = 0; ks < 2; ++ks)
    pa[ks] = *(const short8*)&P[fr][ks * 32 + hi4 * 8];
  floatx4 acc2[4];
#pragma unroll
  for (int j = 0; j < 4; ++j) acc2[j] = (floatx4){0.f, 0.f, 0.f, 0.f};
  const size_t vbase = (size_t)(b * 16) * 2 * 512 + lane * 8;
#pragma unroll
  for (int j = 0; j < 4; ++j) {
    const int vt = w * 4 + j;
    const short8 v0 = *(const short8*)&VtF[vbase + (size_t)(vt * 2 + 0) * 512];
    const short8 v1 = *(const short8*)&VtF[vbase + (size_t)(vt * 2 + 1) * 512];
    acc2[j] = __builtin_amdgcn_mfma_f32_16x16x32_bf16(pa[0], v0, acc2[j], 0, 0, 0);
    acc2[j] = __builtin_amdgcn_mfma_f32_16x16x32_bf16(pa[1], v1, acc2[j], 0, 0, 0);
  }
#pragma unroll
  for (int rr = 0; rr < 4; ++rr) {
    const int tok = t0 + hi4 * 4 + rr;
    const float allowed = hist[tok] ? 0.0f : 1.0f;
#pragma unroll
    for (int j = 0; j < 4; ++j)
      retrB[(size_t)tok * 256 + (w * 4 + j) * 16 + fr] =
          __float2bfloat16(acc2[j][rr] * allowed);
  }
}

// -------- gemm2 classic: x = retrB(16384x256) . WoB^T(2048x256) + hs --------
// 128x128 tile, BK=64, 4 waves (2x2), double-buffered swizzled LDS.
template<int OUTMODE>
__global__ __launch_bounds__(256) void gemm2_kernel(
    const unsigned short* __restrict__ A,
    const unsigned short* __restrict__ Bw,
    const float* __restrict__ RES,
    unsigned short* __restrict__ xB,
    float* __restrict__ xO) {
  const int bm = blockIdx.x >> 4, bn = blockIdx.x & 15;
  const int m0 = bm * 128, n0 = bn * 128;
  const int tid = threadIdx.x;
  const int wid = tid >> 6, lane = tid & 63;
  const int fr = lane & 15, hi4 = lane >> 4;
  const int wr = wid >> 1, wc = wid & 1;

  __shared__ unsigned short As[2][128 * 64];
  __shared__ unsigned short Bs[2][128 * 64];

  floatx4 acc[4][4];
#pragma unroll
  for (int m = 0; m < 4; ++m)
#pragma unroll
    for (int n = 0; n < 4; ++n) acc[m][n] = (floatx4){0.f, 0.f, 0.f, 0.f};

  const int srow = wid * 32 + (lane >> 3);
  const int sc = lane & 7;

  short8 rgA[4], rgB[4];
#define GLOAD(t) do { \
    const int k0 = (t) * 64; \
    _Pragma("unroll") \
    for (int i = 0; i < 4; ++i) { \
      const int row = srow + i * 8; \
      rgA[i] = *(const short8*)&A[(size_t)(m0 + row) * 256 + k0 + sc * 8]; \
      rgB[i] = *(const short8*)&Bw[(size_t)(n0 + row) * 256 + k0 + sc * 8]; \
    } \
  } while (0)
#define LWRITE(buf) do { \
    _Pragma("unroll") \
    for (int i = 0; i < 4; ++i) { \
      const int row = srow + i * 8; \
      const int swz = (sc ^ (row & 7)) * 8; \
      *(short8*)&As[buf][row * 64 + swz] = rgA[i]; \
      *(short8*)&Bs[buf][row * 64 + swz] = rgB[i]; \
    } \
  } while (0)

  GLOAD(0);
  LWRITE(0);

#pragma unroll
  for (int t = 0; t < 4; ++t) {
    const int buf = t & 1;
    if (t < 3) GLOAD(t + 1);
    __syncthreads();
#pragma unroll
    for (int kk = 0; kk < 2; ++kk) {
      short8 af[4], bf[4];
#pragma unroll
      for (int m = 0; m < 4; ++m) {
        const int row = wr * 64 + m * 16 + fr;
        const int chunk = ((kk * 4 + hi4) ^ (row & 7)) * 8;
        af[m] = *(const short8*)&As[buf][row * 64 + chunk];
      }
#pragma unroll
      for (int n = 0; n < 4; ++n) {
        const int row = wc * 64 + n * 16 + fr;
        const int chunk = ((kk * 4 + hi4) ^ (row & 7)) * 8;
        bf[n] = *(const short8*)&Bs[buf][row * 64 + chunk];
      }
#pragma unroll
      for (int m = 0; m < 4; ++m)
#pragma unroll
        for (int n = 0; n < 4; ++n)
          acc[m][n] = __builtin_amdgcn_mfma_f32_16x16x32_bf16(af[m], bf[n],
                                                              acc[m][n], 0, 0, 0);
    }
    if (t < 3) {
      __syncthreads();
      LWRITE(buf ^ 1);
    }
  }

#pragma unroll
  for (int m = 0; m < 4; ++m)
#pragma unroll
    for (int n = 0; n < 4; ++n)
#pragma unroll
      for (int rr = 0; rr < 4; ++rr) {
        const int row = m0 + wr * 64 + m * 16 + hi4 * 4 + rr;
        const int col = n0 + wc * 64 + n * 16 + fr;
        const size_t off = (size_t)row * HH + col;
        const float x = acc[m][n][rr] + RES[off];
        if constexpr (OUTMODE == 0) xB[off] = f2bf(x);
        else xO[off] = x;
      }
#undef GLOAD
#undef LWRITE
}

// -------- LN pass: 1 row/block, 256 thr, 8 elems/thread (NO spill) ----------
template<int BF>
__global__ __launch_bounds__(256) void ln_kernel(
    const void* __restrict__ xin,
    const float* __restrict__ gamma, const float* __restrict__ beta,
    float* __restrict__ out) {
  const int row = blockIdx.x;
  const int tid = threadIdx.x;
  const int c0 = tid * 8;
  float v[8];
  if constexpr (BF) {
    B8 t;
    t.v = *(const short8*)&((const unsigned short*)xin)[(size_t)row * HH + c0];
#pragma unroll
    for (int j = 0; j < 8; ++j) v[j] = bf2f(t.u[j]);
  } else {
    const float* xr = (const float*)xin + (size_t)row * HH + c0;
    const float4 a = *(const float4*)xr;
    const float4 b2 = *(const float4*)(xr + 4);
    v[0] = a.x; v[1] = a.y; v[2] = a.z; v[3] = a.w;
    v[4] = b2.x; v[5] = b2.y; v[6] = b2.z; v[7] = b2.w;
  }
  float s = 0.f, q = 0.f;
#pragma unroll
  for (int j = 0; j < 8; ++j) { s += v[j]; q += v[j] * v[j]; }
#pragma unroll
  for (int o = 32; o; o >>= 1) {
    s += __shfl_xor(s, o);
    q += __shfl_xor(q, o);
  }
  __shared__ float red[4][2];
  if ((tid & 63) == 0) { red[tid >> 6][0] = s; red[tid >> 6][1] = q; }
  __syncthreads();
  s = red[0][0] + red[1][0] + red[2][0] + red[3][0];
  q = red[0][1] + red[1][1] + red[2][1] + red[3][1];
  const float mu = s * (1.0f / HH);
  const float inv = rsqrtf(q * (1.0f / HH) - mu * mu + EPSV);
  const float4 g0 = *(const float4*)&gamma[c0];
  const float4 g1 = *(const float4*)&gamma[c0 + 4];
  const float4 b0 = *(const float4*)&beta[c0];
  const float4 b1 = *(const float4*)&beta[c0 + 4];
  float4 o0, o1;
  o0.x = (v[0] - mu) * inv * g0.x + b0.x;
  o0.y = (v[1] - mu) * inv * g0.y + b0.y;
  o0.z = (v[2] - mu) * inv * g0.z + b0.z;
  o0.w = (v[3] - mu) * inv * g0.w + b0.w;
  o1.x = (v[4] - mu) * inv * g1.x + b1.x;
  o1.y = (v[5] - mu) * inv * g1.y + b1.y;
  o1.z = (v[6] - mu) * inv * g1.z + b1.z;
  o1.w = (v[7] - mu) * inv * g1.w + b1.w;
  float* orow = out + (size_t)row * HH + c0;
  *(float4*)orow = o0;
  *(float4*)(orow + 4) = o1;
}

extern "C" void kernel_launch(void* const* d_in, const int* in_sizes, int n_in,
                              void* d_out, int out_size, void* d_ws, size_t ws_size,
                              hipStream_t stream) {
  const float* hs    = (const float*)d_in[0];
  const float* keys  = (const float*)d_in[1];
  const float* vals  = (const float*)d_in[2];
  const float* Wq    = (const float*)d_in[3];
  const float* Wo    = (const float*)d_in[4];
  const float* gamma = (const float*)d_in[5];
  const float* beta  = (const float*)d_in[6];
  const void* valid_raw = d_in[7];
  const void* hist_raw  = d_in[8];
  float* out = (float*)d_out;

  char* w = (char*)d_ws;
  float* PK            = (float*)w;                           // 2 MB
  unsigned short* PKh  = (unsigned short*)(w + (2u << 20));   // 1 MB
  unsigned short* PKl  = (unsigned short*)(w + (3u << 20));   // 1 MB
  unsigned short* VtF  = (unsigned short*)(w + (4u << 20));   // 256 KB
  unsigned short* WoB  = (unsigned short*)(w + (4u << 20) + (512u << 10)); // 1 MB
  __hip_bfloat16* retrB = (__hip_bfloat16*)(w + (6u << 20));  // 8 MB
  int* valid_int = (int*)(w + (14u << 20));
  int* hist_int  = valid_int + BB * NSLOT;
  unsigned short* xB = (unsigned short*)(w + (15u << 20));    // 64 MB (optional)
  const bool bigws = ws_size >= ((size_t)80u << 20);

  mask_convert_kernel<<<dim3(16), dim3(256), 0, stream>>>(valid_raw, hist_raw,
                                                          valid_int, hist_int);
  pk_kernel<<<dim3(128), dim3(256), 0, stream>>>(keys, Wq, PK);
  frag_prep_kernel<<<dim3(1408), dim3(64), 0, stream>>>(PK, vals, Wo,
                                                        PKh, PKl, VtF, WoB);
  attn_kernel<<<dim3(BT / 16), dim3(256), 0, stream>>>(
      hs, PKh, PKl, VtF, valid_int, hist_int, retrB);
  if (bigws) {
    gemm2_kernel<0><<<dim3((BT / 128) * (HH / 128)), dim3(256), 0, stream>>>(
        (const unsigned short*)retrB, WoB, hs, xB, nullptr);
    ln_kernel<1><<<dim3(BT), dim3(256), 0, stream>>>(xB, gamma, beta, out);
  } else {
    gemm2_kernel<1><<<dim3((BT / 128) * (HH / 128)), dim3(256), 0, stream>>>(
        (const unsigned short*)retrB, WoB, hs, nullptr, out);
    ln_kernel<0><<<dim3(BT), dim3(256), 0, stream>>>(out, gamma, beta, out);
  }
}